// Round 2
// baseline (1196.102 us; speedup 1.0000x reference)
//
#include <hip/hip_runtime.h>
#include <stdint.h>
#include <stdio.h>

#define NOUT 512
#define NSEG 1024

typedef unsigned short u16;
typedef __attribute__((ext_vector_type(4))) float f32x4;
typedef __attribute__((ext_vector_type(8))) short s16x8;
typedef __attribute__((ext_vector_type(4))) unsigned short u16x4;

__device__ __forceinline__ u16 f2b(float f) {
  union { float f; uint32_t u; } v; v.f = f;
  uint32_t r = v.u + 0x7FFFu + ((v.u >> 16) & 1u);
  return (u16)(r >> 16);
}
__device__ __forceinline__ float b2f(u16 b) {
  union { uint32_t u; float f; } v; v.u = ((uint32_t)b) << 16;
  return v.f;
}

typedef __attribute__((address_space(1))) const void GAS;
typedef __attribute__((address_space(3))) void LAS;
__device__ __forceinline__ void llds16(const void* g, void* l) {
  __builtin_amdgcn_global_load_lds((GAS*)g, (LAS*)l, 16, 0, 0);
}

// ---------------- cast kernels ----------------
__global__ void k_cast(const float* __restrict__ src, u16* __restrict__ dst, long n4) {
  long i = blockIdx.x * (long)blockDim.x + threadIdx.x;
  long stride = (long)gridDim.x * blockDim.x;
  for (; i < n4; i += stride) {
    float4 v = reinterpret_cast<const float4*>(src)[i];
    u16x4 o;
    o.x = f2b(v.x); o.y = f2b(v.y); o.z = f2b(v.z); o.w = f2b(v.w);
    reinterpret_cast<u16x4*>(dst)[i] = o;
  }
}

// w: [K][512] f32 -> out: [512][K] bf16 (B^T), coalesced both sides via LDS tile
__global__ void k_wtcastT(const float* __restrict__ w, u16* __restrict__ out, int K) {
  __shared__ float tile[32][33];
  int k0 = blockIdx.x * 32, c0 = blockIdx.y * 32;
  int t = threadIdx.x;  // 256
  int rr = t >> 5, cc = t & 31;
#pragma unroll
  for (int p = 0; p < 4; ++p)
    tile[p * 8 + rr][cc] = w[(long)(k0 + p * 8 + rr) * NOUT + c0 + cc];
  __syncthreads();
#pragma unroll
  for (int p = 0; p < 4; ++p)
    out[(long)(c0 + p * 8 + rr) * K + k0 + cc] = f2b(tile[cc][p * 8 + rr]);
}

// ---------------- segment sort ----------------
__global__ void k_hist(const int* __restrict__ ele, int* __restrict__ cnt, int N) {
  int i = blockIdx.x * blockDim.x + threadIdx.x;
  int stride = gridDim.x * blockDim.x;
  for (; i < N; i += stride) atomicAdd(&cnt[ele[i]], 1);
}

__global__ void k_scan(const int* __restrict__ cnt, int* __restrict__ off) {
  __shared__ int tmp[NSEG];
  int t = threadIdx.x;
  tmp[t] = cnt[t];
  __syncthreads();
  for (int o = 1; o < NSEG; o <<= 1) {
    int add = (t >= o) ? tmp[t - o] : 0;
    __syncthreads();
    tmp[t] += add;
    __syncthreads();
  }
  off[t] = tmp[t] - cnt[t];
}

__global__ void k_scatter(const int* __restrict__ ele, const int* __restrict__ off,
                          int* __restrict__ fill, int* __restrict__ rows, int N) {
  int i = blockIdx.x * blockDim.x + threadIdx.x;
  int stride = gridDim.x * blockDim.x;
  for (; i < N; i += stride) {
    int e = ele[i];
    int p = atomicAdd(&fill[e], 1);
    rows[off[e] + p] = i;
  }
}

// ---------------- BN stats reduce / finalize ----------------
__global__ void k_colreduce(const float* __restrict__ ps, const float* __restrict__ pq,
                            float* __restrict__ sum, float* __restrict__ sq, int rows) {
  int gid = blockIdx.x * blockDim.x + threadIdx.x;  // 64*256 = 16384
  int col = gid & 511;
  int arr = (gid >> 9) & 1;
  int chunk = gid >> 10;  // 0..15
  const float* src = arr ? pq : ps;
  float acc = 0.f;
  for (int r = chunk; r < rows; r += 16) acc += src[(long)r * NOUT + col];
  atomicAdd(arr ? &sq[col] : &sum[col], acc);
}

__global__ void k_finalize(const float* __restrict__ sum, const float* __restrict__ sumsq,
                           const float* __restrict__ g, const float* __restrict__ be,
                           float* __restrict__ A, float* __restrict__ C, int M) {
  int c = threadIdx.x;  // 512
  float m = sum[c] / (float)M;
  float v = sumsq[c] / (float)M - m * m;
  float a = g[c] * rsqrtf(v + 1e-5f);
  A[c] = a;
  C[c] = be[c] - a * m;
}

// ---------------- fused BN-apply + ReLU + segment mean ----------------
__global__ void k_bnseg(const u16* __restrict__ hp, u16* __restrict__ h, u16* __restrict__ mean,
                        const float* __restrict__ A, const float* __restrict__ C,
                        const int* __restrict__ off, const int* __restrict__ cnt,
                        const int* __restrict__ rows) {
  int s = blockIdx.x, t = threadIdx.x;  // 256 threads -> cols 2t,2t+1
  int n = cnt[s], o = off[s];
  int c0 = 2 * t;
  float a0 = A[c0], a1 = A[c0 + 1], cc0 = C[c0], cc1 = C[c0 + 1];
  float s0 = 0.f, s1 = 0.f;
  for (int j = 0; j < n; ++j) {
    int r = rows[o + j];
    uint32_t v = *reinterpret_cast<const uint32_t*>(&hp[(long)r * NOUT + c0]);
    float h0 = fmaxf(a0 * b2f((u16)(v & 0xffff)) + cc0, 0.f);
    float h1 = fmaxf(a1 * b2f((u16)(v >> 16)) + cc1, 0.f);
    s0 += h0; s1 += h1;
    *reinterpret_cast<uint32_t*>(&h[(long)r * NOUT + c0]) =
        ((uint32_t)f2b(h1) << 16) | (uint32_t)f2b(h0);
  }
  float inv = 1.f / fmaxf((float)n, 1.f);
  *reinterpret_cast<uint32_t*>(&mean[(long)s * NOUT + c0]) =
      ((uint32_t)f2b(s1 * inv) << 16) | (uint32_t)f2b(s0 * inv);
}

__global__ void k_final(const u16* __restrict__ hp, float* __restrict__ out,
                        const float* __restrict__ A, const float* __restrict__ C, long n4) {
  long i = blockIdx.x * (long)blockDim.x + threadIdx.x;
  long stride = (long)gridDim.x * blockDim.x;
  for (; i < n4; i += stride) {
    u16x4 v = reinterpret_cast<const u16x4*>(hp)[i];
    int c0 = (int)((i * 4) & (NOUT - 1));
    float4 a = *reinterpret_cast<const float4*>(&A[c0]);
    float4 c = *reinterpret_cast<const float4*>(&C[c0]);
    float4 o;
    o.x = fmaxf(a.x * b2f(v.x) + c.x, 0.f);
    o.y = fmaxf(a.y * b2f(v.y) + c.y, 0.f);
    o.z = fmaxf(a.z * b2f(v.z) + c.z, 0.f);
    o.w = fmaxf(a.w * b2f(v.w) + c.w, 0.f);
    reinterpret_cast<float4*>(out)[i] = o;
  }
}

// ---------------- GEMM: C[M,512] = A[M,K] @ W[K,512], BM=BN=256, BK=32 ----------------
// Triple-buffered LDS, counted vmcnt(4), 1 barrier/K-tile, XOR-swizzled folded [128][64] tiles.
// A has 3 source regions (ptr/width/gather/start); wbt is W^T [512][K] bf16.
// Epilogue writes pre-BN bf16 C + per-(mtile*2+wr) column sum/sumsq partials (bias dropped: cancels in BN).
__global__ __launch_bounds__(512, 2) void k_gemm(
    const u16* p0, const u16* p1, const u16* p2,
    int e0, int e1, int w0, int w1, int w2,
    int g0, int g1, int g2,
    const int* __restrict__ ele, const u16* __restrict__ wbt,
    u16* __restrict__ outp, float* __restrict__ ps, float* __restrict__ pq,
    int M, int K) {
  __shared__ __align__(16) u16 As[3 * 8192];
  __shared__ __align__(16) u16 Bs[3 * 8192];

  int nwg = gridDim.x;
  int bid0 = blockIdx.x;
  // bijective XCD swizzle (m204)
  int qq = nwg >> 3, rr2 = nwg & 7;
  int xcd = bid0 & 7, loc = bid0 >> 3;
  int bid = (xcd < rr2 ? xcd * (qq + 1) : rr2 * (qq + 1) + (xcd - rr2) * qq) + loc;
  int mt = bid >> 1;
  int ct = bid & 1;
  int brow = mt * 256, bcol = ct * 256;

  int tid = (int)threadIdx.x;
  int lane = tid & 63;
  int wid = tid >> 6;               // 0..7
  int wr = wid >> 2, wc = wid & 3;  // 2 x 4 waves, per-wave 128x64
  int l15 = lane & 15, kg = lane >> 4;

  // ---- staging geometry: folded [128][64] layout, swz(byte) = byte ^ (((byte>>7)&7)<<4) ----
  int t3 = tid & 7, t8 = tid >> 3;       // t8 in 0..63
  int x = t3 ^ (t8 & 7);
  int hi = x >> 2;
  int cpr = (x & 3) * 8;                 // element col offset (0..24)

  int gr0 = brow + t8 + 128 * hi;
  int gr1 = gr0 + 64;
  int gr0c = gr0 < M ? gr0 : M - 1;
  int gr1c = gr1 < M ? gr1 : M - 1;
  int el0 = ele[gr0c], el1 = ele[gr1c];

  const u16* a00 = p0 + (long)(g0 ? el0 : gr0c) * w0 + cpr;
  const u16* a01 = p1 + (long)(g1 ? el0 : gr0c) * w1 + cpr - e0;
  const u16* a02 = p2 + (long)(g2 ? el0 : gr0c) * w2 + cpr - e1;
  const u16* a10 = p0 + (long)(g0 ? el1 : gr1c) * w0 + cpr;
  const u16* a11 = p1 + (long)(g1 ? el1 : gr1c) * w1 + cpr - e0;
  const u16* a12 = p2 + (long)(g2 ? el1 : gr1c) * w2 + cpr - e1;

  int gc0 = bcol + t8 + 128 * hi;        // < 512 always
  const u16* b0p = wbt + (long)gc0 * K + cpr;
  const u16* b1p = b0p + (long)64 * K;

  // frag read offsets (u16 index, lane-const)
  int aro = (l15 * 128 + (((wr * 4 + kg) ^ (l15 & 7)) << 4)) >> 1;
  int bro = ((((wc & 1) * 64 + l15) * 128 + ((((wc >> 1) * 4 + kg) ^ (l15 & 7)) << 4)) >> 1);

  f32x4 acc[8][4];
#pragma unroll
  for (int m = 0; m < 8; ++m)
#pragma unroll
    for (int n = 0; n < 4; ++n)
#pragma unroll
      for (int j = 0; j < 4; ++j) acc[m][n][j] = 0.f;

  int KT = K >> 5;

  auto stageA = [&](int tt) {
    int k0 = tt << 5;
    int rs = (k0 >= e0) + (k0 >= e1);
    const u16* s0p = rs == 0 ? a00 : (rs == 1 ? a01 : a02);
    const u16* s1p = rs == 0 ? a10 : (rs == 1 ? a11 : a12);
    u16* d = &As[(tt % 3) * 8192 + wid * 512];
    llds16(s0p + k0, d);
    llds16(s1p + k0, d + 4096);
  };
  auto stageB = [&](int tt) {
    int k0 = tt << 5;
    u16* d = &Bs[(tt % 3) * 8192 + wid * 512];
    llds16(b0p + k0, d);
    llds16(b1p + k0, d + 4096);
  };

  // prologue: tiles 0 and 1 in flight
  stageA(0); stageB(0);
  stageA(1); stageB(1);

  for (int t = 0; t < KT; ++t) {
    if (t == KT - 1) {
      asm volatile("s_waitcnt vmcnt(0)" ::: "memory");
    } else {
      asm volatile("s_waitcnt vmcnt(4)" ::: "memory");
    }
    __builtin_amdgcn_s_barrier();
    __builtin_amdgcn_sched_barrier(0);
    const u16* Ab = &As[(t % 3) * 8192];
    const u16* Bb = &Bs[(t % 3) * 8192];
    s16x8 bf[4], af[4];
#pragma unroll
    for (int n = 0; n < 4; ++n)
      bf[n] = *reinterpret_cast<const s16x8*>(&Bb[n * 1024 + bro]);
#pragma unroll
    for (int m = 0; m < 4; ++m)
      af[m] = *reinterpret_cast<const s16x8*>(&Ab[m * 1024 + aro]);
    if (t + 2 < KT) stageA(t + 2);
    __builtin_amdgcn_s_setprio(1);
#pragma unroll
    for (int m = 0; m < 4; ++m)
#pragma unroll
      for (int n = 0; n < 4; ++n)
        acc[m][n] = __builtin_amdgcn_mfma_f32_16x16x32_bf16(af[m], bf[n], acc[m][n], 0, 0, 0);
    __builtin_amdgcn_s_setprio(0);
#pragma unroll
    for (int m = 0; m < 4; ++m)
      af[m] = *reinterpret_cast<const s16x8*>(&Ab[(4 + m) * 1024 + aro]);
    if (t + 2 < KT) stageB(t + 2);
    __builtin_amdgcn_s_setprio(1);
#pragma unroll
    for (int m = 0; m < 4; ++m)
#pragma unroll
      for (int n = 0; n < 4; ++n)
        acc[4 + m][n] = __builtin_amdgcn_mfma_f32_16x16x32_bf16(af[m], bf[n], acc[4 + m][n], 0, 0, 0);
    __builtin_amdgcn_s_setprio(0);
  }

  // epilogue: C-write (col=lane&15, row=kg*4+j) + column stats partials
  float sums[4] = {0.f, 0.f, 0.f, 0.f}, sqs[4] = {0.f, 0.f, 0.f, 0.f};
#pragma unroll
  for (int m = 0; m < 8; ++m) {
    int row0 = brow + wr * 128 + m * 16 + kg * 4;
#pragma unroll
    for (int n = 0; n < 4; ++n) {
      int col = bcol + wc * 64 + n * 16 + l15;
#pragma unroll
      for (int j = 0; j < 4; ++j) {
        int r = row0 + j;
        if (r < M) {
          float v = acc[m][n][j];
          outp[(long)r * NOUT + col] = f2b(v);
          sums[n] += v;
          sqs[n] += v * v;
        }
      }
    }
  }
#pragma unroll
  for (int n = 0; n < 4; ++n) {
    sums[n] += __shfl_xor(sums[n], 16);
    sums[n] += __shfl_xor(sums[n], 32);
    sqs[n] += __shfl_xor(sqs[n], 16);
    sqs[n] += __shfl_xor(sqs[n], 32);
  }
  if (kg == 0) {
    long prow = (long)(mt * 2 + wr) * NOUT;
#pragma unroll
    for (int n = 0; n < 4; ++n) {
      int col = bcol + wc * 64 + n * 16 + l15;
      ps[prow + col] = sums[n];
      pq[prow + col] = sqs[n];
    }
  }
}

// ---------------- host ----------------
extern "C" void kernel_launch(void* const* d_in, const int* in_sizes, int n_in,
                              void* d_out, int out_size, void* d_ws, size_t ws_size,
                              hipStream_t stream) {
  const float* x    = (const float*)d_in[0];
  const float* dist = (const float*)d_in[1];
  const int* ele    = (const int*)d_in[3];
  const float* l1w  = (const float*)d_in[4];
  const float* l1g  = (const float*)d_in[6];
  const float* l1be = (const float*)d_in[7];
  const float* l2w  = (const float*)d_in[8];
  const float* l2g  = (const float*)d_in[10];
  const float* l2be = (const float*)d_in[11];
  const float* fw   = (const float*)d_in[12];
  const float* fg   = (const float*)d_in[14];
  const float* fbe  = (const float*)d_in[15];

  int N = in_sizes[0] / 1024;  // 100000
  float* out = (float*)d_out;
  u16* xbf = (u16*)d_out;      // bf16 x overlays d_out (exact size match, dead by final write)

  int MT = (N + 255) / 256;    // 391
  int prows = MT * 2;

  char* w = (char*)d_ws;
  auto alloc = [&](size_t bytes) {
    char* p = w;
    w += (bytes + 255) & ~(size_t)255;
    return p;
  };
  u16* dist_bf = (u16*)alloc((size_t)N * 256 * 2);
  u16* hp      = (u16*)alloc((size_t)N * NOUT * 2);
  u16* h       = (u16*)alloc((size_t)N * NOUT * 2);
  u16* mean    = (u16*)alloc((size_t)NSEG * NOUT * 2);
  u16* w1bt    = (u16*)alloc((size_t)NOUT * 1280 * 2);
  u16* w2bt    = (u16*)alloc((size_t)NOUT * 1280 * 2);
  u16* fbt     = (u16*)alloc((size_t)NOUT * 1024 * 2);
  float* ps    = (float*)alloc((size_t)prows * NOUT * 4);
  float* pq    = (float*)alloc((size_t)prows * NOUT * 4);
  float* colsum = (float*)alloc(NOUT * 4 * 2);  // sum + sumsq adjacent
  float* colsumsq = colsum + NOUT;
  float* bnA   = (float*)alloc(NOUT * 4);
  float* bnC   = (float*)alloc(NOUT * 4);
  int* seg_cnt = (int*)alloc(NSEG * 4);
  int* seg_off = (int*)alloc(NSEG * 4);
  int* seg_fill = (int*)alloc(NSEG * 4);
  int* rows    = (int*)alloc((size_t)N * 4);

  size_t need = (size_t)(w - (char*)d_ws);
  if (need > ws_size) {
    fprintf(stderr, "kernel_launch: ws too small: need %zu have %zu\n", need, ws_size);
    return;
  }

  long n4x = (long)N * 1024 / 4;
  long n4d = (long)N * 256 / 4;
  long n4h = (long)N * NOUT / 4;
  int gemmGrid = MT * 2;  // 782

  // casts
  k_cast<<<4096, 256, 0, stream>>>(x, xbf, n4x);
  k_cast<<<2048, 256, 0, stream>>>(dist, dist_bf, n4d);
  dim3 wt1(1280 / 32, 16), wt3(1024 / 32, 16);
  k_wtcastT<<<wt1, 256, 0, stream>>>(l1w, w1bt, 1280);
  k_wtcastT<<<wt1, 256, 0, stream>>>(l2w, w2bt, 1280);
  k_wtcastT<<<wt3, 256, 0, stream>>>(fw, fbt, 1024);

  // segment sort
  hipMemsetAsync(seg_cnt, 0, NSEG * 4, stream);
  hipMemsetAsync(seg_fill, 0, NSEG * 4, stream);
  k_hist<<<512, 256, 0, stream>>>(ele, seg_cnt, N);
  k_scan<<<1, NSEG, 0, stream>>>(seg_cnt, seg_off);
  k_scatter<<<512, 256, 0, stream>>>(ele, seg_off, seg_fill, rows, N);

  // ---- layer 1: A = [x(1024) | dist(256)] ----
  k_gemm<<<gemmGrid, 512, 0, stream>>>(xbf, dist_bf, dist_bf, 1024, 1280, 1024, 256, 256,
                                       0, 0, 0, ele, w1bt, hp, ps, pq, N, 1280);
  hipMemsetAsync(colsum, 0, NOUT * 4 * 2, stream);
  k_colreduce<<<64, 256, 0, stream>>>(ps, pq, colsum, colsumsq, prows);
  k_finalize<<<1, NOUT, 0, stream>>>(colsum, colsumsq, l1g, l1be, bnA, bnC, N);
  k_bnseg<<<NSEG, 256, 0, stream>>>(hp, h, mean, bnA, bnC, seg_off, seg_cnt, rows);

  // ---- layer 2: A = [h(512) | mean[ele](512) | dist(256)] ----
  k_gemm<<<gemmGrid, 512, 0, stream>>>(h, mean, dist_bf, 512, 1024, 512, 512, 256,
                                       0, 1, 0, ele, w2bt, hp, ps, pq, N, 1280);
  hipMemsetAsync(colsum, 0, NOUT * 4 * 2, stream);
  k_colreduce<<<64, 256, 0, stream>>>(ps, pq, colsum, colsumsq, prows);
  k_finalize<<<1, NOUT, 0, stream>>>(colsum, colsumsq, l2g, l2be, bnA, bnC, N);
  k_bnseg<<<NSEG, 256, 0, stream>>>(hp, h, mean, bnA, bnC, seg_off, seg_cnt, rows);

  // ---- final layer: A = [h(512) | mean[ele](512)] ----
  k_gemm<<<gemmGrid, 512, 0, stream>>>(h, mean, mean, 512, 1024, 512, 512, 512,
                                       0, 1, 1, ele, fbt, hp, ps, pq, N, 1024);
  hipMemsetAsync(colsum, 0, NOUT * 4 * 2, stream);
  k_colreduce<<<64, 256, 0, stream>>>(ps, pq, colsum, colsumsq, prows);
  k_finalize<<<1, NOUT, 0, stream>>>(colsum, colsumsq, fg, fbe, bnA, bnC, N);
  k_final<<<4096, 256, 0, stream>>>(hp, out, bnA, bnC, n4h);
}